// Round 7
// baseline (44.042 us; speedup 1.0000x reference)
//
#include <hip/hip_runtime.h>
#include <stdint.h>

#define N_PTS   512
#define N_NODES 10000
#define N_EDGES 50000
#define N_CMP   64
#define W64     784             // u64 words per bit-plane row; 784*64 = 50176
#define EBITS   (W64 * 64)      // 50176
#define LSTRIDE (N_CMP * W64)   // per-plane stride, L
#define NCHUNK  49
#define CW      16              // words per chunk = 1024 edges
#define TN      32              // points per group (u32 bsT)
#define NGRP    (N_PTS / TN)    // 16
#define BST_ROW 10016           // padded node count (16B-aligned rows)
#define NB_BST  ((N_NODES + 255) / 256)   // 40 node-blocks per group
#define NBLK_L  (NCHUNK * N_CMP)          // 3136 build_L blocks

typedef unsigned long long u64;

// ---------------- Kernel A (fused): build_L + build_bsT ----------------
// L planes: la=p3|p4, lb=p2|p4, tz=p0 (one-hot => tl==0 <=> p0). Pad -> tz=1.
// float4 loads, nibble-pack via LDS, 48 packer threads/block.
__global__ void build_all(const int* __restrict__ act, const float* __restrict__ BL,
                          u64* __restrict__ Lp, uint32_t* __restrict__ bsT) {
    int bid = blockIdx.x;
    int t = threadIdx.x;
    if (bid < NBLK_L) {
        __shared__ uint16_t sh[256];
        int c = bid / NCHUNK, bx = bid % NCHUNK;    // c row, 1024-edge block
        int e0 = bx * 1024 + 4 * t;
        int nla = 0, nlb = 0, ntz = 0xF;
        if (e0 < N_EDGES) {                          // N_EDGES%4==0: all-or-none
            const float* base = BL + (size_t)c * (5 * N_EDGES) + e0;
            float4 p0 = *(const float4*)(base);
            float4 p2 = *(const float4*)(base + 2 * N_EDGES);
            float4 p3 = *(const float4*)(base + 3 * N_EDGES);
            float4 p4 = *(const float4*)(base + 4 * N_EDGES);
            #define B_(f) ((f) != 0.f ? 1 : 0)
            nla = (B_(p3.x) | B_(p4.x)) | ((B_(p3.y) | B_(p4.y)) << 1)
                | ((B_(p3.z) | B_(p4.z)) << 2) | ((B_(p3.w) | B_(p4.w)) << 3);
            nlb = (B_(p2.x) | B_(p4.x)) | ((B_(p2.y) | B_(p4.y)) << 1)
                | ((B_(p2.z) | B_(p4.z)) << 2) | ((B_(p2.w) | B_(p4.w)) << 3);
            ntz = B_(p0.x) | (B_(p0.y) << 1) | (B_(p0.z) << 2) | (B_(p0.w) << 3);
            #undef B_
        }
        sh[t] = (uint16_t)(nla | (nlb << 4) | (ntz << 8));
        __syncthreads();
        if (t < 48) {                                // plane p, word w of 16
            int p = t >> 4, w = t & 15;
            const u64* v = (const u64*)sh + w * 4;   // 4 u64 = 16 u16 nibble-sources
            u64 word = 0;
            #pragma unroll
            for (int i = 0; i < 4; ++i) {
                u64 x = v[i];
                #pragma unroll
                for (int kk = 0; kk < 4; ++kk)
                    word |= ((x >> (16 * kk + 4 * p)) & 0xFULL) << (4 * (i * 4 + kk));
            }
            Lp[(size_t)p * LSTRIDE + (size_t)c * W64 + bx * 16 + w] = word;
        }
    } else {
        // transposed bitsets: bit p of bsT[g][node] = act[g*32+p][node] != 0
        int rem = bid - NBLK_L;
        int g = rem / NB_BST, nb = rem % NB_BST;
        int node = nb * 256 + t;
        if (node < N_NODES) {
            uint32_t m = 0;
            #pragma unroll
            for (int p = 0; p < TN; ++p)
                m |= (act[(size_t)(g * TN + p) * N_NODES + node] != 0 ? 1u : 0u) << p;
            bsT[(size_t)g * BST_ROW + node] = m;
        }
    }
}

// ---------------- Kernel C (fused): in-register Q ballots + mismatch popcount ----------------
// Block (chunk, group): 512 thr = 8 waves; wave owns points {wave, wave+8, +16, +24}.
// Edges live in registers (coalesced L2 loads); bsT row + transposed L in LDS.
__global__ void __launch_bounds__(512, 4)
match_fused(const u64* __restrict__ Lp, const uint32_t* __restrict__ bsT,
            const int2* __restrict__ edges, uint2* __restrict__ part) {
    __shared__ u64 Ll[3][CW][65];                   // 24.96 KB (pad 65)
    __shared__ uint32_t bsTl[BST_ROW];              // 40.06 KB

    int chunk = blockIdx.x;                         // 0..48
    int g = blockIdx.y;                             // 0..15
    int t = threadIdx.x;
    int lane = t & 63;
    int wave = t >> 6;                              // 0..7
    int cw0 = chunk * CW;

    // Edges into registers: 16 coalesced wave-loads (tail-clamped; pads tz-masked).
    int2 ereg[CW];
    int ebase = chunk * 1024 + lane;
    #pragma unroll
    for (int w = 0; w < CW; ++w)
        ereg[w] = edges[min(ebase + w * 64, N_EDGES - 1)];

    // Stage L transposed: 192 rows (plane,c) x 16 words, coalesced 128B segments.
    {
        int w = t & 15;
        #pragma unroll
        for (int pass = 0; pass < 6; ++pass) {
            int r = pass * 32 + (t >> 4);           // 0..191
            int plane = r >> 6, c = r & 63;
            Ll[plane][w][c] = Lp[(size_t)plane * LSTRIDE + (size_t)c * W64 + cw0 + w];
        }
    }
    // Stage bsT row: 40064 B as 2504 uint4, coalesced.
    {
        const uint4* src = (const uint4*)(bsT + (size_t)g * BST_ROW);
        uint4* dst = (uint4*)bsTl;
        for (int idx = t; idx < BST_ROW / 4; idx += 512) dst[idx] = src[idx];
    }
    __syncthreads();

    int cnt0 = 0, cnt1 = 0, cnt2 = 0, cnt3 = 0;
    #pragma unroll
    for (int w = 0; w < CW; ++w) {
        int2 cur = ereg[w];
        uint32_t a = bsTl[cur.x];
        uint32_t b = bsTl[cur.y];
        u64 A0 = __ballot((a >> wave) & 1);
        u64 B0 = __ballot((b >> wave) & 1);
        u64 A1 = __ballot((a >> (wave + 8)) & 1);
        u64 B1 = __ballot((b >> (wave + 8)) & 1);
        u64 A2 = __ballot((a >> (wave + 16)) & 1);
        u64 B2 = __ballot((b >> (wave + 16)) & 1);
        u64 A3 = __ballot((a >> (wave + 24)) & 1);
        u64 B3 = __ballot((b >> (wave + 24)) & 1);
        u64 la = Ll[0][w][lane];
        u64 lb = Ll[1][w][lane];
        u64 tz = Ll[2][w][lane];
        cnt0 += __popcll(tz | (la ^ A0) | (lb ^ B0));
        cnt1 += __popcll(tz | (la ^ A1) | (lb ^ B1));
        cnt2 += __popcll(tz | (la ^ A2) | (lb ^ B2));
        cnt3 += __popcll(tz | (la ^ A3) | (lb ^ B3));
    }
    part[(((size_t)chunk * NGRP + g) * 8 + wave) * 64 + lane] =
        make_uint2((uint32_t)cnt0 | ((uint32_t)cnt1 << 16),
                   (uint32_t)cnt2 | ((uint32_t)cnt3 << 16));
}

// ---------------- Kernel D1: sum chunks, energy = EBITS - mismatches, block min ----------------
__global__ void reduce1(const uint2* __restrict__ part, int* __restrict__ energy,
                        int* __restrict__ blockmin) {
    int t = blockIdx.x * 256 + threadIdx.x;         // (n,c)
    int c = t & 63, n = t >> 6;
    int g = n >> 5, p = n & 31;
    int wv = p & 7, jj = p >> 3;                    // point = wv + 8*jj
    int sh = (jj & 1) * 16;
    int s = 0;
    #pragma unroll 7
    for (int ch = 0; ch < NCHUNK; ++ch) {
        uint2 v = part[(((size_t)ch * NGRP + g) * 8 + wv) * 64 + c];
        uint32_t word = (jj < 2) ? v.x : v.y;
        s += (word >> sh) & 0xFFFF;
    }
    int e = EBITS - s;
    energy[t] = e;
    int m = e;
    for (int off = 32; off; off >>= 1) m = min(m, __shfl_down(m, off, 64));
    __shared__ int wm[4];
    if ((threadIdx.x & 63) == 0) wm[threadIdx.x >> 6] = m;
    __syncthreads();
    if (threadIdx.x == 0) blockmin[blockIdx.x] = min(min(wm[0], wm[1]), min(wm[2], wm[3]));
}

// ---------------- Kernel D2: global min (redone per block) + subtract ----------------
__global__ void subk(const int* __restrict__ energy, const int* __restrict__ blockmin,
                     float* __restrict__ out) {
    __shared__ int wm[4];
    __shared__ int ms;
    int t = threadIdx.x;
    int m = t < 128 ? blockmin[t] : 0x7fffffff;
    for (int off = 32; off; off >>= 1) m = min(m, __shfl_down(m, off, 64));
    if ((t & 63) == 0) wm[t >> 6] = m;
    __syncthreads();
    if (t == 0) ms = min(wm[0], wm[1]);
    __syncthreads();
    int mv = ms;
    int i = blockIdx.x * 256 + t;
    int4 e = ((const int4*)energy)[i];
    ((float4*)out)[i] = make_float4((float)(e.x - mv), (float)(e.y - mv),
                                    (float)(e.z - mv), (float)(e.w - mv));
}

extern "C" void kernel_launch(void* const* d_in, const int* in_sizes, int n_in,
                              void* d_out, int out_size, void* d_ws, size_t ws_size,
                              hipStream_t stream) {
    const int*   act   = (const int*)d_in[0];       // 512 x 10000
    const float* BL    = (const float*)d_in[1];     // 64 x 250000
    const int2*  edges = (const int2*)d_in[2];      // 50000 x 2
    float* out = (float*)d_out;

    u64* Lp = (u64*)d_ws;                                   // 3*64*784 u64 = 1.204 MB
    uint32_t* bsT = (uint32_t*)(Lp + 3 * (size_t)LSTRIDE);  // 16*10016 u32 = 641 KB
    uint2* part = (uint2*)(bsT + (size_t)NGRP * BST_ROW);   // 49*16*8*64 uint2 = 3.21 MB
    int* energy   = (int*)(part + (size_t)NCHUNK * NGRP * 8 * 64); // 32768 int
    int* blockmin = energy + N_PTS * N_CMP;                 // 128 int

    build_all   <<<NBLK_L + NGRP * NB_BST, 256, 0, stream>>>(act, BL, Lp, bsT);
    match_fused <<<dim3(NCHUNK, NGRP), 512, 0, stream>>>(Lp, bsT, edges, part);
    reduce1     <<<N_PTS * N_CMP / 256, 256, 0, stream>>>(part, energy, blockmin);
    subk        <<<N_PTS * N_CMP / 1024, 256, 0, stream>>>(energy, blockmin, out);
}

// Round 8
// 40.768 us; speedup vs baseline: 1.0803x; 1.0803x over previous
//
#include <hip/hip_runtime.h>
#include <stdint.h>

#define N_PTS   512
#define N_NODES 10000
#define N_EDGES 50000
#define N_CMP   64
#define W64     784             // u64 words per bit-plane row; 784*64 = 50176
#define EBITS   (W64 * 64)      // 50176
#define LSTRIDE (N_CMP * W64)   // per-plane stride, L
#define NCHUNK  49
#define CW      16              // words per chunk = 1024 edges
#define TN      16              // points per group (u16 bsT)
#define NGRP    (N_PTS / TN)    // 32
#define BST_ROW 10016           // padded node count (16B-aligned rows)
#define NB_BST  ((N_NODES + 255) / 256)   // 40 node-blocks per group
#define NBLK_L  (NCHUNK * N_CMP)          // 3136 build_L blocks

typedef unsigned long long u64;

// ---------------- Kernel A (fused): build_L + build_bsT ----------------
// L planes: la=p3|p4, lb=p2|p4, tz=p0 (one-hot => tl==0 <=> p0). Pad -> tz=1.
// float4 loads, nibble-pack via LDS, 48 packer threads/block.
__global__ void build_all(const int* __restrict__ act, const float* __restrict__ BL,
                          u64* __restrict__ Lp, uint16_t* __restrict__ bsT) {
    int bid = blockIdx.x;
    int t = threadIdx.x;
    if (bid < NBLK_L) {
        __shared__ uint16_t sh[256];
        int c = bid / NCHUNK, bx = bid % NCHUNK;    // c row, 1024-edge block
        int e0 = bx * 1024 + 4 * t;
        int nla = 0, nlb = 0, ntz = 0xF;
        if (e0 < N_EDGES) {                          // N_EDGES%4==0: all-or-none
            const float* base = BL + (size_t)c * (5 * N_EDGES) + e0;
            float4 p0 = *(const float4*)(base);
            float4 p2 = *(const float4*)(base + 2 * N_EDGES);
            float4 p3 = *(const float4*)(base + 3 * N_EDGES);
            float4 p4 = *(const float4*)(base + 4 * N_EDGES);
            #define B_(f) ((f) != 0.f ? 1 : 0)
            nla = (B_(p3.x) | B_(p4.x)) | ((B_(p3.y) | B_(p4.y)) << 1)
                | ((B_(p3.z) | B_(p4.z)) << 2) | ((B_(p3.w) | B_(p4.w)) << 3);
            nlb = (B_(p2.x) | B_(p4.x)) | ((B_(p2.y) | B_(p4.y)) << 1)
                | ((B_(p2.z) | B_(p4.z)) << 2) | ((B_(p2.w) | B_(p4.w)) << 3);
            ntz = B_(p0.x) | (B_(p0.y) << 1) | (B_(p0.z) << 2) | (B_(p0.w) << 3);
            #undef B_
        }
        sh[t] = (uint16_t)(nla | (nlb << 4) | (ntz << 8));
        __syncthreads();
        if (t < 48) {                                // plane p, word w of 16
            int p = t >> 4, w = t & 15;
            const u64* v = (const u64*)sh + w * 4;   // 4 u64 = 16 u16 nibble-sources
            u64 word = 0;
            #pragma unroll
            for (int i = 0; i < 4; ++i) {
                u64 x = v[i];
                #pragma unroll
                for (int kk = 0; kk < 4; ++kk)
                    word |= ((x >> (16 * kk + 4 * p)) & 0xFULL) << (4 * (i * 4 + kk));
            }
            Lp[(size_t)p * LSTRIDE + (size_t)c * W64 + bx * 16 + w] = word;
        }
    } else {
        // transposed bitsets: bit p of bsT[g][node] = act[g*16+p][node] != 0
        int rem = bid - NBLK_L;
        int g = rem / NB_BST, nb = rem % NB_BST;
        int node = nb * 256 + t;
        if (node < N_NODES) {
            uint32_t m = 0;
            #pragma unroll
            for (int p = 0; p < TN; ++p)
                m |= (act[(size_t)(g * TN + p) * N_NODES + node] != 0 ? 1u : 0u) << p;
            bsT[(size_t)g * BST_ROW + node] = (uint16_t)m;
        }
    }
}

// ---------------- Kernel C (fused): word-owner waves ----------------
// Block (chunk, group): 512 thr = 8 waves. Wave wv owns words {2wv, 2wv+1},
// computing ALL 16 points (cnt[16] in VGPRs). Per word: 1 coalesced edge load
// (L2-resident), 2 u16 LDS gathers, 32 ballots, 3 L b64 reads, 16 popc-accums.
// Block LDS ops cut 8x vs point-owner layout (no cross-wave duplicate reads).
// Epilogue: packed-u16 cross-wave reduction in LDS aliased over dead bsTl.
__global__ void __launch_bounds__(512, 6)
match_fused(const u64* __restrict__ Lp, const uint16_t* __restrict__ bsT,
            const int2* __restrict__ edges, uint32_t* __restrict__ part32) {
    __shared__ u64 Ll[3][CW][65];                   // 24.96 KB (pad 65)
    __shared__ __align__(16) uint16_t bsTl[BST_ROW];// 20.03 KB (reused as red32)

    int chunk = blockIdx.x;                         // 0..48
    int g = blockIdx.y;                             // 0..31
    int t = threadIdx.x;
    int lane = t & 63;
    int wave = t >> 6;                              // 0..7
    int cw0 = chunk * CW;

    // Stage L transposed: 192 rows (plane,c) x 16 words, 128B segments.
    {
        int w = t & 15;
        #pragma unroll
        for (int pass = 0; pass < 6; ++pass) {
            int r = pass * 32 + (t >> 4);           // 0..191
            int plane = r >> 6, c = r & 63;
            Ll[plane][w][c] = Lp[(size_t)plane * LSTRIDE + (size_t)c * W64 + cw0 + w];
        }
    }
    // Stage bsT row: 20032 B as 1252 uint4, coalesced.
    {
        const uint4* src = (const uint4*)(bsT + (size_t)g * BST_ROW);
        uint4* dst = (uint4*)bsTl;
        for (int idx = t; idx < BST_ROW / 8; idx += 512) dst[idx] = src[idx];
    }
    __syncthreads();

    uint32_t cnt[TN];
    #pragma unroll
    for (int p = 0; p < TN; ++p) cnt[p] = 0;

    #pragma unroll
    for (int j = 0; j < 2; ++j) {
        int w = wave * 2 + j;
        int2 cur = edges[min(chunk * 1024 + w * 64 + lane, N_EDGES - 1)];
        uint32_t a16 = bsTl[cur.x];
        uint32_t b16 = bsTl[cur.y];
        u64 la = Ll[0][w][lane];
        u64 lb = Ll[1][w][lane];
        u64 tz = Ll[2][w][lane];
        #pragma unroll
        for (int p = 0; p < TN; ++p) {
            u64 A = __ballot((a16 >> p) & 1);
            u64 B = __ballot((b16 >> p) & 1);
            cnt[p] += __popcll(tz | (la ^ A) | (lb ^ B));
        }
    }

    // Cross-wave reduction: pack (cnt[2q], cnt[2q+1]) into u32; halves can't
    // carry (max 8 waves * 128 = 1024 < 65536). red32 aliases dead bsTl.
    __syncthreads();
    uint32_t (*red32)[8][64] = (uint32_t (*)[8][64])bsTl;
    #pragma unroll
    for (int q = 0; q < 8; ++q)
        red32[wave][q][lane] = cnt[2 * q] | (cnt[2 * q + 1] << 16);
    __syncthreads();
    {
        int q = t >> 6, c = t & 63;                 // 512 threads = all (q,c)
        uint32_t s = 0;
        #pragma unroll
        for (int wv = 0; wv < 8; ++wv) s += red32[wv][q][c];
        part32[(((size_t)chunk * NGRP + g) * 8 + q) * 64 + c] = s;
    }
}

// ---------------- Kernel D1: sum chunks, energy = EBITS - mismatches, block min ----------------
__global__ void reduce1(const uint32_t* __restrict__ part32, int* __restrict__ energy,
                        int* __restrict__ blockmin) {
    int t = blockIdx.x * 256 + threadIdx.x;         // t = n*64 + c
    int c = t & 63, n = t >> 6;
    int g = n >> 4, p = n & 15;
    int q = p >> 1, hi = (p & 1) * 16;
    int s = 0;
    #pragma unroll 7
    for (int ch = 0; ch < NCHUNK; ++ch)
        s += (part32[(((size_t)ch * NGRP + g) * 8 + q) * 64 + c] >> hi) & 0xFFFF;
    int e = EBITS - s;
    energy[t] = e;
    int m = e;
    for (int off = 32; off; off >>= 1) m = min(m, __shfl_down(m, off, 64));
    __shared__ int wm[4];
    if ((threadIdx.x & 63) == 0) wm[threadIdx.x >> 6] = m;
    __syncthreads();
    if (threadIdx.x == 0) blockmin[blockIdx.x] = min(min(wm[0], wm[1]), min(wm[2], wm[3]));
}

// ---------------- Kernel D2: global min (redone per block) + subtract ----------------
__global__ void subk(const int* __restrict__ energy, const int* __restrict__ blockmin,
                     float* __restrict__ out) {
    __shared__ int wm[4];
    __shared__ int ms;
    int t = threadIdx.x;
    int m = t < 128 ? blockmin[t] : 0x7fffffff;
    for (int off = 32; off; off >>= 1) m = min(m, __shfl_down(m, off, 64));
    if ((t & 63) == 0) wm[t >> 6] = m;
    __syncthreads();
    if (t == 0) ms = min(wm[0], wm[1]);
    __syncthreads();
    int mv = ms;
    int i = blockIdx.x * 256 + t;
    int4 e = ((const int4*)energy)[i];
    ((float4*)out)[i] = make_float4((float)(e.x - mv), (float)(e.y - mv),
                                    (float)(e.z - mv), (float)(e.w - mv));
}

extern "C" void kernel_launch(void* const* d_in, const int* in_sizes, int n_in,
                              void* d_out, int out_size, void* d_ws, size_t ws_size,
                              hipStream_t stream) {
    const int*   act   = (const int*)d_in[0];       // 512 x 10000
    const float* BL    = (const float*)d_in[1];     // 64 x 250000
    const int2*  edges = (const int2*)d_in[2];      // 50000 x 2
    float* out = (float*)d_out;

    u64* Lp = (u64*)d_ws;                                   // 3*64*784 u64 = 1.204 MB
    uint16_t* bsT = (uint16_t*)(Lp + 3 * (size_t)LSTRIDE);  // 32*10016 u16 = 641 KB
    uint32_t* part32 = (uint32_t*)(bsT + (size_t)NGRP * BST_ROW); // 49*32*8*64 u32 = 3.21 MB
    int* energy   = (int*)(part32 + (size_t)NCHUNK * NGRP * 8 * 64); // 32768 int
    int* blockmin = energy + N_PTS * N_CMP;                 // 128 int

    build_all   <<<NBLK_L + NGRP * NB_BST, 256, 0, stream>>>(act, BL, Lp, bsT);
    match_fused <<<dim3(NCHUNK, NGRP), 512, 0, stream>>>(Lp, bsT, edges, part32);
    reduce1     <<<N_PTS * N_CMP / 256, 256, 0, stream>>>(part32, energy, blockmin);
    subk        <<<N_PTS * N_CMP / 1024, 256, 0, stream>>>(energy, blockmin, out);
}

// Round 9
// 40.356 us; speedup vs baseline: 1.0913x; 1.0102x over previous
//
#include <hip/hip_runtime.h>
#include <stdint.h>

#define N_PTS   512
#define N_NODES 10000
#define N_EDGES 50000
#define N_CMP   64
#define W64     784             // u64 words per bit-plane row; 784*64 = 50176
#define EBITS   (W64 * 64)      // 50176
#define LSTRIDE (N_CMP * W64)   // per-plane stride, L
#define NCHUNK  49
#define CW      16              // words per chunk = 1024 edges
#define TN      16              // points per group (u16 bsT)
#define NGRP    (N_PTS / TN)    // 32
#define BST_ROW 10016           // padded node count (16B-aligned rows)
#define NB_BST  ((N_NODES + 255) / 256)   // 40 node-blocks per group
#define NBLK_L  (NCHUNK * N_CMP)          // 3136 build_L blocks
#define E32SZ   (NGRP * 8 * 64)           // 16384 packed-u32 energy slots

typedef unsigned long long u64;

// ---------------- Kernel A (fused): build_L + build_bsT + energy32 zero ----------------
// L planes: la=p3|p4, lb=p2|p4, tz=p0 (one-hot => tl==0 <=> p0). Pad -> tz=1.
// float4 loads, nibble-pack via LDS, 48 packer threads/block.
__global__ void build_all(const int* __restrict__ act, const float* __restrict__ BL,
                          u64* __restrict__ Lp, uint16_t* __restrict__ bsT,
                          uint32_t* __restrict__ energy32) {
    int bid = blockIdx.x;
    int t = threadIdx.x;
    if (bid < E32SZ / 256) energy32[bid * 256 + t] = 0;   // re-zeroed every launch
    if (bid < NBLK_L) {
        __shared__ uint16_t sh[256];
        int c = bid / NCHUNK, bx = bid % NCHUNK;    // c row, 1024-edge block
        int e0 = bx * 1024 + 4 * t;
        int nla = 0, nlb = 0, ntz = 0xF;
        if (e0 < N_EDGES) {                          // N_EDGES%4==0: all-or-none
            const float* base = BL + (size_t)c * (5 * N_EDGES) + e0;
            float4 p0 = *(const float4*)(base);
            float4 p2 = *(const float4*)(base + 2 * N_EDGES);
            float4 p3 = *(const float4*)(base + 3 * N_EDGES);
            float4 p4 = *(const float4*)(base + 4 * N_EDGES);
            #define B_(f) ((f) != 0.f ? 1 : 0)
            nla = (B_(p3.x) | B_(p4.x)) | ((B_(p3.y) | B_(p4.y)) << 1)
                | ((B_(p3.z) | B_(p4.z)) << 2) | ((B_(p3.w) | B_(p4.w)) << 3);
            nlb = (B_(p2.x) | B_(p4.x)) | ((B_(p2.y) | B_(p4.y)) << 1)
                | ((B_(p2.z) | B_(p4.z)) << 2) | ((B_(p2.w) | B_(p4.w)) << 3);
            ntz = B_(p0.x) | (B_(p0.y) << 1) | (B_(p0.z) << 2) | (B_(p0.w) << 3);
            #undef B_
        }
        sh[t] = (uint16_t)(nla | (nlb << 4) | (ntz << 8));
        __syncthreads();
        if (t < 48) {                                // plane p, word w of 16
            int p = t >> 4, w = t & 15;
            const u64* v = (const u64*)sh + w * 4;   // 4 u64 = 16 u16 nibble-sources
            u64 word = 0;
            #pragma unroll
            for (int i = 0; i < 4; ++i) {
                u64 x = v[i];
                #pragma unroll
                for (int kk = 0; kk < 4; ++kk)
                    word |= ((x >> (16 * kk + 4 * p)) & 0xFULL) << (4 * (i * 4 + kk));
            }
            Lp[(size_t)p * LSTRIDE + (size_t)c * W64 + bx * 16 + w] = word;
        }
    } else {
        // transposed bitsets: bit p of bsT[g][node] = act[g*16+p][node] != 0
        int rem = bid - NBLK_L;
        int g = rem / NB_BST, nb = rem % NB_BST;
        int node = nb * 256 + t;
        if (node < N_NODES) {
            uint32_t m = 0;
            #pragma unroll
            for (int p = 0; p < TN; ++p)
                m |= (act[(size_t)(g * TN + p) * N_NODES + node] != 0 ? 1u : 0u) << p;
            bsT[(size_t)g * BST_ROW + node] = (uint16_t)m;
        }
    }
}

// ---------------- Kernel C (fused): word-owner waves + packed atomic accumulate ----------------
// Block (chunk, group): 512 thr = 8 waves. Wave wv owns words {2wv, 2wv+1},
// computing ALL 16 points (cnt[16] in VGPRs). Cross-wave LDS reduction, then
// ONE packed-u32 atomicAdd per thread into energy32[(g*8+q)*64+c].
// Halves can't carry: per-half total <= 49*1024 = 50176 < 65536. Int atomics
// are order-independent bit-exact -> deterministic under graph replay.
__global__ void __launch_bounds__(512, 6)
match_fused(const u64* __restrict__ Lp, const uint16_t* __restrict__ bsT,
            const int2* __restrict__ edges, uint32_t* __restrict__ energy32) {
    __shared__ u64 Ll[3][CW][65];                   // 24.96 KB (pad 65)
    __shared__ __align__(16) uint16_t bsTl[BST_ROW];// 20.03 KB (reused as red32)

    int chunk = blockIdx.x;                         // 0..48
    int g = blockIdx.y;                             // 0..31
    int t = threadIdx.x;
    int lane = t & 63;
    int wave = t >> 6;                              // 0..7
    int cw0 = chunk * CW;

    // Stage L transposed: 192 rows (plane,c) x 16 words, 128B segments.
    {
        int w = t & 15;
        #pragma unroll
        for (int pass = 0; pass < 6; ++pass) {
            int r = pass * 32 + (t >> 4);           // 0..191
            int plane = r >> 6, c = r & 63;
            Ll[plane][w][c] = Lp[(size_t)plane * LSTRIDE + (size_t)c * W64 + cw0 + w];
        }
    }
    // Stage bsT row: 20032 B as 1252 uint4, coalesced.
    {
        const uint4* src = (const uint4*)(bsT + (size_t)g * BST_ROW);
        uint4* dst = (uint4*)bsTl;
        for (int idx = t; idx < BST_ROW / 8; idx += 512) dst[idx] = src[idx];
    }
    __syncthreads();

    uint32_t cnt[TN];
    #pragma unroll
    for (int p = 0; p < TN; ++p) cnt[p] = 0;

    #pragma unroll
    for (int j = 0; j < 2; ++j) {
        int w = wave * 2 + j;
        int2 cur = edges[min(chunk * 1024 + w * 64 + lane, N_EDGES - 1)];
        uint32_t a16 = bsTl[cur.x];
        uint32_t b16 = bsTl[cur.y];
        u64 la = Ll[0][w][lane];
        u64 lb = Ll[1][w][lane];
        u64 tz = Ll[2][w][lane];
        #pragma unroll
        for (int p = 0; p < TN; ++p) {
            u64 A = __ballot((a16 >> p) & 1);
            u64 B = __ballot((b16 >> p) & 1);
            cnt[p] += __popcll(tz | (la ^ A) | (lb ^ B));
        }
    }

    // Cross-wave reduction: pack (cnt[2q], cnt[2q+1]) into u32 (max 8*128=1024
    // per half, no carry). red32 aliases dead bsTl.
    __syncthreads();
    uint32_t (*red32)[8][64] = (uint32_t (*)[8][64])bsTl;
    #pragma unroll
    for (int q = 0; q < 8; ++q)
        red32[wave][q][lane] = cnt[2 * q] | (cnt[2 * q + 1] << 16);
    __syncthreads();
    {
        int q = t >> 6, c = t & 63;                 // 512 threads = all (q,c)
        uint32_t s = 0;
        #pragma unroll
        for (int wv = 0; wv < 8; ++wv) s += red32[wv][q][c];
        atomicAdd(&energy32[(g * 8 + q) * 64 + c], s);
    }
}

// ---------------- Kernel E: finalize ----------------
// energies - min(energies) == max_mis - mis. 32 blocks; each block redundantly
// max-reduces the 64 KB energy32 (L2-hit) then writes its 1024-output slice.
__global__ void finalize(const uint32_t* __restrict__ energy32, float* __restrict__ out) {
    __shared__ int wm[4];
    __shared__ int ms;
    int t = threadIdx.x;
    int mx = 0;
    const uint4* e4 = (const uint4*)energy32;
    for (int i = t; i < E32SZ / 4; i += 256) {      // 16 iters
        uint4 v = e4[i];
        mx = max(mx, (int)(v.x & 0xFFFF)); mx = max(mx, (int)(v.x >> 16));
        mx = max(mx, (int)(v.y & 0xFFFF)); mx = max(mx, (int)(v.y >> 16));
        mx = max(mx, (int)(v.z & 0xFFFF)); mx = max(mx, (int)(v.z >> 16));
        mx = max(mx, (int)(v.w & 0xFFFF)); mx = max(mx, (int)(v.w >> 16));
    }
    for (int off = 32; off; off >>= 1) mx = max(mx, __shfl_down(mx, off, 64));
    if ((t & 63) == 0) wm[t >> 6] = mx;
    __syncthreads();
    if (t == 0) ms = max(max(wm[0], wm[1]), max(wm[2], wm[3]));
    __syncthreads();
    int mxv = ms;
    #pragma unroll
    for (int k = 0; k < 4; ++k) {
        int o = blockIdx.x * 1024 + k * 256 + t;    // output index (n*64+c)
        int n = o >> 6, c = o & 63;
        int g = n >> 4, p = n & 15, q = p >> 1, h = p & 1;
        uint32_t w = energy32[(g * 8 + q) * 64 + c];
        int s = (int)((w >> (16 * h)) & 0xFFFF);
        out[o] = (float)(mxv - s);
    }
}

extern "C" void kernel_launch(void* const* d_in, const int* in_sizes, int n_in,
                              void* d_out, int out_size, void* d_ws, size_t ws_size,
                              hipStream_t stream) {
    const int*   act   = (const int*)d_in[0];       // 512 x 10000
    const float* BL    = (const float*)d_in[1];     // 64 x 250000
    const int2*  edges = (const int2*)d_in[2];      // 50000 x 2
    float* out = (float*)d_out;

    u64* Lp = (u64*)d_ws;                                   // 3*64*784 u64 = 1.204 MB
    uint16_t* bsT = (uint16_t*)(Lp + 3 * (size_t)LSTRIDE);  // 32*10016 u16 = 641 KB
    uint32_t* energy32 = (uint32_t*)(bsT + (size_t)NGRP * BST_ROW); // 16384 u32 = 64 KB

    build_all   <<<NBLK_L + NGRP * NB_BST, 256, 0, stream>>>(act, BL, Lp, bsT, energy32);
    match_fused <<<dim3(NCHUNK, NGRP), 512, 0, stream>>>(Lp, bsT, edges, energy32);
    finalize    <<<32, 256, 0, stream>>>(energy32, out);
}

// Round 10
// 39.327 us; speedup vs baseline: 1.1199x; 1.0262x over previous
//
#include <hip/hip_runtime.h>
#include <stdint.h>

#define N_PTS   512
#define N_NODES 10000
#define N_EDGES 50000
#define N_CMP   64
#define W64     784             // u64 words per bit-plane row; 784*64 = 50176
#define EBITS   (W64 * 64)      // 50176
#define NCHUNK  49
#define CW      16              // words per chunk = 1024 edges
#define TN      16              // points per group (u16 bsT)
#define NGRP    (N_PTS / TN)    // 32
#define BST_ROW 10016           // padded node count (16B-aligned rows)
#define NB_BST  ((N_NODES + 255) / 256)   // 40 node-blocks per group
#define NBLK_L  (NCHUNK * N_CMP)          // 3136 build_L blocks
#define E32SZ   (NGRP * 8 * 64)           // 16384 packed-u32 energy slots

typedef unsigned long long u64;

// LpT layout: LpT[(plane*W64 + gw)*64 + c] -- c contiguous, so a wave reading
// word gw for all 64 c's is one coalesced 512B load (L2-resident, 1.2 MB).

// ---------------- Kernel A (fused): build_LpT + build_bsT + energy32 zero ----------------
// L planes: la=p3|p4, lb=p2|p4, tz=p0 (one-hot => tl==0 <=> p0). Pad -> tz=1.
// float4 loads, nibble-pack via LDS, 48 packer threads/block.
__global__ void build_all(const int* __restrict__ act, const float* __restrict__ BL,
                          u64* __restrict__ LpT, uint16_t* __restrict__ bsT,
                          uint32_t* __restrict__ energy32) {
    int bid = blockIdx.x;
    int t = threadIdx.x;
    if (bid < E32SZ / 256) energy32[bid * 256 + t] = 0;   // re-zeroed every launch
    if (bid < NBLK_L) {
        __shared__ uint16_t sh[256];
        int c = bid / NCHUNK, bx = bid % NCHUNK;    // c row, 1024-edge block
        int e0 = bx * 1024 + 4 * t;
        int nla = 0, nlb = 0, ntz = 0xF;
        if (e0 < N_EDGES) {                          // N_EDGES%4==0: all-or-none
            const float* base = BL + (size_t)c * (5 * N_EDGES) + e0;
            float4 p0 = *(const float4*)(base);
            float4 p2 = *(const float4*)(base + 2 * N_EDGES);
            float4 p3 = *(const float4*)(base + 3 * N_EDGES);
            float4 p4 = *(const float4*)(base + 4 * N_EDGES);
            #define B_(f) ((f) != 0.f ? 1 : 0)
            nla = (B_(p3.x) | B_(p4.x)) | ((B_(p3.y) | B_(p4.y)) << 1)
                | ((B_(p3.z) | B_(p4.z)) << 2) | ((B_(p3.w) | B_(p4.w)) << 3);
            nlb = (B_(p2.x) | B_(p4.x)) | ((B_(p2.y) | B_(p4.y)) << 1)
                | ((B_(p2.z) | B_(p4.z)) << 2) | ((B_(p2.w) | B_(p4.w)) << 3);
            ntz = B_(p0.x) | (B_(p0.y) << 1) | (B_(p0.z) << 2) | (B_(p0.w) << 3);
            #undef B_
        }
        sh[t] = (uint16_t)(nla | (nlb << 4) | (ntz << 8));
        __syncthreads();
        if (t < 48) {                                // plane p, word w of 16
            int p = t >> 4, w = t & 15;
            const u64* v = (const u64*)sh + w * 4;   // 4 u64 = 16 u16 nibble-sources
            u64 word = 0;
            #pragma unroll
            for (int i = 0; i < 4; ++i) {
                u64 x = v[i];
                #pragma unroll
                for (int kk = 0; kk < 4; ++kk)
                    word |= ((x >> (16 * kk + 4 * p)) & 0xFULL) << (4 * (i * 4 + kk));
            }
            LpT[((size_t)p * W64 + bx * 16 + w) * 64 + c] = word;
        }
    } else {
        // transposed bitsets: bit p of bsT[g][node] = act[g*16+p][node] != 0
        int rem = bid - NBLK_L;
        int g = rem / NB_BST, nb = rem % NB_BST;
        int node = nb * 256 + t;
        if (node < N_NODES) {
            uint32_t m = 0;
            #pragma unroll
            for (int p = 0; p < TN; ++p)
                m |= (act[(size_t)(g * TN + p) * N_NODES + node] != 0 ? 1u : 0u) << p;
            bsT[(size_t)g * BST_ROW + node] = (uint16_t)m;
        }
    }
}

// ---------------- Kernel C: word-owner waves, direct-L reads, atomic accumulate ----------------
// Block (chunk, group): 512 thr = 8 waves. Wave wv owns words {2wv, 2wv+1},
// computing ALL 16 points (cnt[16] in VGPRs). L read DIRECTLY from transposed
// global (coalesced 512B wave-loads, L2-resident) -- no Ll staging, no barrier.
// Only bsT row staged in LDS (20 KB -> 4 blocks/CU, 32 waves/CU).
// Epilogue: packed-u16 cross-wave LDS reduction, one u32 atomicAdd per thread.
// Halves can't carry (<= 50176 < 65536); int atomics bit-exact deterministic.
__global__ void __launch_bounds__(512, 8)
match_fused(const u64* __restrict__ LpT, const uint16_t* __restrict__ bsT,
            const int2* __restrict__ edges, uint32_t* __restrict__ energy32) {
    __shared__ __align__(16) uint16_t bsTl[BST_ROW];// 20.03 KB (reused as red32)

    int chunk = blockIdx.x;                         // 0..48
    int g = blockIdx.y;                             // 0..31
    int t = threadIdx.x;
    int lane = t & 63;
    int wave = t >> 6;                              // 0..7

    // Stage bsT row: 20032 B as 1252 uint4, coalesced.
    {
        const uint4* src = (const uint4*)(bsT + (size_t)g * BST_ROW);
        uint4* dst = (uint4*)bsTl;
        for (int idx = t; idx < BST_ROW / 8; idx += 512) dst[idx] = src[idx];
    }
    __syncthreads();

    uint32_t cnt[TN];
    #pragma unroll
    for (int p = 0; p < TN; ++p) cnt[p] = 0;

    #pragma unroll
    for (int j = 0; j < 2; ++j) {
        int w = wave * 2 + j;                       // word within chunk
        int gw = chunk * CW + w;                    // global word index
        int2 cur = edges[min(chunk * 1024 + w * 64 + lane, N_EDGES - 1)];
        u64 la = LpT[((size_t)0 * W64 + gw) * 64 + lane];
        u64 lb = LpT[((size_t)1 * W64 + gw) * 64 + lane];
        u64 tz = LpT[((size_t)2 * W64 + gw) * 64 + lane];
        uint32_t a16 = bsTl[cur.x];
        uint32_t b16 = bsTl[cur.y];
        #pragma unroll
        for (int p = 0; p < TN; ++p) {
            u64 A = __ballot((a16 >> p) & 1);
            u64 B = __ballot((b16 >> p) & 1);
            cnt[p] += __popcll(tz | (la ^ A) | (lb ^ B));
        }
    }

    // Cross-wave reduction: pack (cnt[2q], cnt[2q+1]) into u32 (max 8*128=1024
    // per half, no carry). red32 aliases dead bsTl (16 KB <= 20 KB).
    __syncthreads();
    uint32_t (*red32)[8][64] = (uint32_t (*)[8][64])bsTl;
    #pragma unroll
    for (int q = 0; q < 8; ++q)
        red32[wave][q][lane] = cnt[2 * q] | (cnt[2 * q + 1] << 16);
    __syncthreads();
    {
        int q = t >> 6, c = t & 63;                 // 512 threads = all (q,c)
        uint32_t s = 0;
        #pragma unroll
        for (int wv = 0; wv < 8; ++wv) s += red32[wv][q][c];
        atomicAdd(&energy32[(g * 8 + q) * 64 + c], s);
    }
}

// ---------------- Kernel E: finalize ----------------
// energies - min(energies) == max_mis - mis. 32 blocks; each block redundantly
// max-reduces the 64 KB energy32 (L2-hit) then writes its 1024-output slice.
__global__ void finalize(const uint32_t* __restrict__ energy32, float* __restrict__ out) {
    __shared__ int wm[4];
    __shared__ int ms;
    int t = threadIdx.x;
    int mx = 0;
    const uint4* e4 = (const uint4*)energy32;
    for (int i = t; i < E32SZ / 4; i += 256) {      // 16 iters
        uint4 v = e4[i];
        mx = max(mx, (int)(v.x & 0xFFFF)); mx = max(mx, (int)(v.x >> 16));
        mx = max(mx, (int)(v.y & 0xFFFF)); mx = max(mx, (int)(v.y >> 16));
        mx = max(mx, (int)(v.z & 0xFFFF)); mx = max(mx, (int)(v.z >> 16));
        mx = max(mx, (int)(v.w & 0xFFFF)); mx = max(mx, (int)(v.w >> 16));
    }
    for (int off = 32; off; off >>= 1) mx = max(mx, __shfl_down(mx, off, 64));
    if ((t & 63) == 0) wm[t >> 6] = mx;
    __syncthreads();
    if (t == 0) ms = max(max(wm[0], wm[1]), max(wm[2], wm[3]));
    __syncthreads();
    int mxv = ms;
    #pragma unroll
    for (int k = 0; k < 4; ++k) {
        int o = blockIdx.x * 1024 + k * 256 + t;    // output index (n*64+c)
        int n = o >> 6, c = o & 63;
        int g = n >> 4, p = n & 15, q = p >> 1, h = p & 1;
        uint32_t w = energy32[(g * 8 + q) * 64 + c];
        int s = (int)((w >> (16 * h)) & 0xFFFF);
        out[o] = (float)(mxv - s);
    }
}

extern "C" void kernel_launch(void* const* d_in, const int* in_sizes, int n_in,
                              void* d_out, int out_size, void* d_ws, size_t ws_size,
                              hipStream_t stream) {
    const int*   act   = (const int*)d_in[0];       // 512 x 10000
    const float* BL    = (const float*)d_in[1];     // 64 x 250000
    const int2*  edges = (const int2*)d_in[2];      // 50000 x 2
    float* out = (float*)d_out;

    u64* LpT = (u64*)d_ws;                                  // 3*784*64 u64 = 1.204 MB
    uint16_t* bsT = (uint16_t*)(LpT + 3 * (size_t)W64 * 64);// 32*10016 u16 = 641 KB
    uint32_t* energy32 = (uint32_t*)(bsT + (size_t)NGRP * BST_ROW); // 16384 u32 = 64 KB

    build_all   <<<NBLK_L + NGRP * NB_BST, 256, 0, stream>>>(act, BL, LpT, bsT, energy32);
    match_fused <<<dim3(NCHUNK, NGRP), 512, 0, stream>>>(LpT, bsT, edges, energy32);
    finalize    <<<32, 256, 0, stream>>>(energy32, out);
}